// Round 9
// baseline (76.058 us; speedup 1.0000x reference)
//
#include <hip/hip_runtime.h>

#define P 7
#define NCH 256
#define NPP 49
#define LDS_CAP 1280   // proven max padded region = ~1089 floats; 18% margin

__global__ __launch_bounds__(256) void pooler_kernel(
    const float* __restrict__ boxes,
    const int* __restrict__ batch_ids,
    const float* __restrict__ f0, const float* __restrict__ f1,
    const float* __restrict__ f2, const float* __restrict__ f3,
    float* __restrict__ out)
{
    __shared__ float sreg[4][LDS_CAP];   // 20 KB: one region per channel-wave

    const int n    = blockIdx.y;          // box
    const int cg   = blockIdx.x;          // channel group 0..63
    const int lane = threadIdx.x;         // 0..63
    const int wy   = threadIdx.y;         // wave = channel within group
    const int c    = cg * 4 + wy;

    // ---- box + level (uniform within block) ----
    const float x1i = boxes[n*4+0], y1i = boxes[n*4+1];
    const float x2i = boxes[n*4+2], y2i = boxes[n*4+3];
    const float area = (x2i - x1i) * (y2i - y1i);
    float lvlf = floorf(4.0f + log2f(sqrtf(area) / 224.0f + 1e-6f));
    lvlf = fminf(fmaxf(lvlf, 2.0f), 5.0f);
    const int lvl = (int)lvlf - 2;        // 0..3

    const float* feat = (lvl==0) ? f0 : (lvl==1) ? f1 : (lvl==2) ? f2 : f3;
    const int    L    = (lvl==0) ? 200 : (lvl==1) ? 100 : (lvl==2) ? 50 : 25;
    const float scale = (lvl==0) ? 0.25f : (lvl==1) ? 0.125f
                      : (lvl==2) ? 0.0625f : 0.03125f;
    const int b = batch_ids[n];

    const float x1 = x1i * scale, y1 = y1i * scale;
    const float bw = fmaxf(x2i*scale - x1, 1.0f) * (1.0f/7.0f);
    const float bh = fmaxf(y2i*scale - y1, 1.0f) * (1.0f/7.0f);
    const float Lf = (float)L, Lm1 = Lf - 1.0f;
    const int   Lm2 = L - 2;

    // ---- region bounds: prep_lo is monotone in coord; samples span g in [0.25, 6.75]
    const float fx1c = fminf(fmaxf(x1 + 0.25f*bw, 0.0f), Lm1);
    const float fx2c = fminf(fmaxf(x1 + 6.75f*bw, 0.0f), Lm1);
    const float fy1c = fminf(fmaxf(y1 + 0.25f*bh, 0.0f), Lm1);
    const float fy2c = fminf(fmaxf(y1 + 6.75f*bh, 0.0f), Lm1);
    const int rx0 = min((int)fx1c, Lm2);
    const int rx1 = min((int)fx2c, Lm2);
    const int ry0 = min((int)fy1c, Lm2);
    const int ry1 = min((int)fy2c, Lm2);
    const int Wr = rx1 - rx0 + 2;         // region cols (covers x0..x0+1 of all taps)
    const int Hr = ry1 - ry0 + 2;         // region rows
    const int stride = Wr | 1;            // odd LDS row stride -> bank-friendly
    const int T  = Wr * Hr;
    const float rcpW = 1.0f / (float)Wr;

    const float* plane = feat + ((size_t)b * NCH + c) * (size_t)(L * L);

    // ---- stage region -> LDS (coalesced: consecutive lanes = consecutive cols) ----
    const int nIter = (T + 63) >> 6;      // uniform across all 4 waves (same T)
    for (int it = 0; it < nIter; ++it) {
        const int f = it * 64 + lane;
        if (f < T) {
            // row = floor(f / Wr) via float rcp; (f+0.5)/Wr margin 0.5/130 >> rcp err
            const int row = (int)(((float)f + 0.5f) * rcpW);
            const int col = f - row * Wr;
            const int idx = row * stride + col;
            if (idx < LDS_CAP)            // provably true; guards LDS corruption
                sreg[wy][idx] = plane[(ry0 + row) * L + rx0 + col];
        }
    }
    __syncthreads();

    // ---- bilinear interpolation from LDS (lanes 0..48 = bins) ----
    if (lane < NPP) {
        const int py = lane / P;
        const int px = lane - py * P;

        float acc = 0.0f;
#pragma unroll
        for (int sy = 0; sy < 2; ++sy) {
            const float yc  = y1 + ((float)py + (sy ? 0.75f : 0.25f)) * bh;
            const float vy  = (yc > -1.0f && yc < Lf) ? 1.0f : 0.0f;
            const float ycc = fminf(fmaxf(yc, 0.0f), Lm1);
            const int   y0  = min((int)ycc, Lm2);
            const float fy  = ycc - (float)y0;
            const float hy  = 1.0f - fy;
            const int abase = (y0 - ry0) * stride - rx0;
#pragma unroll
            for (int sx = 0; sx < 2; ++sx) {
                const float xc  = x1 + ((float)px + (sx ? 0.75f : 0.25f)) * bw;
                const float vx  = (xc > -1.0f && xc < Lf) ? 1.0f : 0.0f;
                const float xcc = fminf(fmaxf(xc, 0.0f), Lm1);
                const int   x0  = min((int)xcc, Lm2);
                const float fx  = xcc - (float)x0;
                const float hx  = 1.0f - fx;

                const int a = abase + x0;             // in [0, Hr*stride) by construction
                const float v00 = sreg[wy][a];
                const float v01 = sreg[wy][a + 1];
                const float v10 = sreg[wy][a + stride];
                const float v11 = sreg[wy][a + stride + 1];

                acc += (vy * vx) * (hy * (hx * v00 + fx * v01)
                                  + fy * (hx * v10 + fx * v11));
            }
        }
        out[((size_t)n * NCH + c) * NPP + lane] = acc * 0.25f;
    }
}

extern "C" void kernel_launch(void* const* d_in, const int* in_sizes, int n_in,
                              void* d_out, int out_size, void* d_ws, size_t ws_size,
                              hipStream_t stream) {
    const float* boxes     = (const float*)d_in[0];
    const int*   batch_ids = (const int*)d_in[1];
    const float* f0        = (const float*)d_in[2];
    const float* f1        = (const float*)d_in[3];
    const float* f2        = (const float*)d_in[4];
    const float* f3        = (const float*)d_in[5];
    float* out = (float*)d_out;

    const int N = in_sizes[0] / 4;                 // 512
    dim3 block(64, 4);                             // 4 waves = 4 channels
    dim3 grid(NCH / 4, N);                         // (64, 512)
    pooler_kernel<<<grid, block, 0, stream>>>(boxes, batch_ids, f0, f1, f2, f3, out);
}

// Round 10
// 74.585 us; speedup vs baseline: 1.0198x; 1.0198x over previous
//
#include <hip/hip_runtime.h>

#define P 7
#define NCH 256
#define NPP 49
#define CPT 4                       // channels per thread
#define CG (NCH / CPT)              // 64 channel groups

typedef float f2 __attribute__((ext_vector_type(2), aligned(4)));

__global__ __launch_bounds__(256) void pooler_kernel(
    const float* __restrict__ boxes,
    const int* __restrict__ batch_ids,
    const float* __restrict__ g0, const float* __restrict__ g1,
    const float* __restrict__ g2, const float* __restrict__ g3,
    float* __restrict__ out, int total)
{
    const int tid = blockIdx.x * 256 + threadIdx.x;
    if (tid >= total) return;            // grid tiles exactly; never taken

    // tid -> (n, cg, bin)
    const int n   = tid / (CG * NPP);
    const int r   = tid - n * (CG * NPP);
    const int cg  = r / NPP;
    const int bin = r - cg * NPP;
    const int py  = bin / P;
    const int px  = bin - py * P;

    // ---- box + level ----
    const float x1i = boxes[n*4+0], y1i = boxes[n*4+1];
    const float x2i = boxes[n*4+2], y2i = boxes[n*4+3];
    const float area = (x2i - x1i) * (y2i - y1i);
    float lvlf = floorf(4.0f + log2f(sqrtf(area) / 224.0f + 1e-6f));
    lvlf = fminf(fmaxf(lvlf, 2.0f), 5.0f);
    const int lvl = (int)lvlf - 2;       // 0..3

    const float* feat = (lvl==0) ? g0 : (lvl==1) ? g1 : (lvl==2) ? g2 : g3;
    const int    L    = (lvl==0) ? 200 : (lvl==1) ? 100 : (lvl==2) ? 50 : 25;
    const float scale = (lvl==0) ? 0.25f : (lvl==1) ? 0.125f
                      : (lvl==2) ? 0.0625f : 0.03125f;
    const int b = batch_ids[n];
    const int LL = L * L;

    const float x1 = x1i * scale, y1 = y1i * scale;
    const float bw = fmaxf(x2i*scale - x1, 1.0f) * (1.0f/7.0f);
    const float bh = fmaxf(y2i*scale - y1, 1.0f) * (1.0f/7.0f);
    const float Lf = (float)L, Lm1 = Lf - 1.0f;
    const int   Lm2 = L - 2;

    // ---- per-axis sample prep (2 subsamples each axis), shared across 4 channels
    int   y0[2], x0[2];
    float fy[2], hy[2], vy[2], fx[2], hx[2], vx[2];
#pragma unroll
    for (int s = 0; s < 2; ++s) {
        const float gy = (float)py + (s ? 0.75f : 0.25f);
        const float yc = y1 + gy * bh;
        vy[s] = (yc > -1.0f && yc < Lf) ? 1.0f : 0.0f;
        const float ycc = fminf(fmaxf(yc, 0.0f), Lm1);
        y0[s] = min((int)ycc, Lm2);
        fy[s] = ycc - (float)y0[s];
        hy[s] = 1.0f - fy[s];

        const float gx = (float)px + (s ? 0.75f : 0.25f);
        const float xc = x1 + gx * bw;
        vx[s] = (xc > -1.0f && xc < Lf) ? 1.0f : 0.0f;
        const float xcc = fminf(fmaxf(xc, 0.0f), Lm1);
        x0[s] = min((int)xcc, Lm2);
        fx[s] = xcc - (float)x0[s];
        hx[s] = 1.0f - fx[s];
    }

    const float* pb = feat + ((size_t)b * NCH + cg * CPT) * (size_t)LL;

    float acc0 = 0.0f, acc1 = 0.0f, acc2 = 0.0f, acc3 = 0.0f;
#pragma unroll
    for (int sy = 0; sy < 2; ++sy) {
#pragma unroll
        for (int sx = 0; sx < 2; ++sx) {
            const int   off = y0[sy] * L + x0[sx];
            const float w   = vy[sy] * vx[sx];
            const float whh = w * hy[sy] * hx[sx];
            const float whl = w * hy[sy] * fx[sx];
            const float wlh = w * fy[sy] * hx[sx];
            const float wll = w * fy[sy] * fx[sx];

            // 8B row-pair loads: (v00,v01) and (v10,v11) per channel plane
            const f2 a0 = *(const f2*)(pb + 0*LL + off);
            const f2 b0 = *(const f2*)(pb + 0*LL + off + L);
            const f2 a1 = *(const f2*)(pb + 1*LL + off);
            const f2 b1 = *(const f2*)(pb + 1*LL + off + L);
            const f2 a2 = *(const f2*)(pb + 2*LL + off);
            const f2 b2 = *(const f2*)(pb + 2*LL + off + L);
            const f2 a3 = *(const f2*)(pb + 3*LL + off);
            const f2 b3 = *(const f2*)(pb + 3*LL + off + L);

            acc0 += whh*a0.x + whl*a0.y + wlh*b0.x + wll*b0.y;
            acc1 += whh*a1.x + whl*a1.y + wlh*b1.x + wll*b1.y;
            acc2 += whh*a2.x + whl*a2.y + wlh*b2.x + wll*b2.y;
            acc3 += whh*a3.x + whl*a3.y + wlh*b3.x + wll*b3.y;
        }
    }

    const size_t obase = ((size_t)n * NCH + cg * CPT) * NPP + bin;
    out[obase + 0*NPP] = acc0 * 0.25f;
    out[obase + 1*NPP] = acc1 * 0.25f;
    out[obase + 2*NPP] = acc2 * 0.25f;
    out[obase + 3*NPP] = acc3 * 0.25f;
}

extern "C" void kernel_launch(void* const* d_in, const int* in_sizes, int n_in,
                              void* d_out, int out_size, void* d_ws, size_t ws_size,
                              hipStream_t stream) {
    const float* boxes     = (const float*)d_in[0];
    const int*   batch_ids = (const int*)d_in[1];
    const float* g0        = (const float*)d_in[2];
    const float* g1        = (const float*)d_in[3];
    const float* g2        = (const float*)d_in[4];
    const float* g3        = (const float*)d_in[5];
    float* out = (float*)d_out;

    const int N = in_sizes[0] / 4;                  // 512
    const int total = N * CG * NPP;                 // 1,605,632 = 6272 * 256
    const int blocks = (total + 255) / 256;
    pooler_kernel<<<blocks, 256, 0, stream>>>(boxes, batch_ids, g0, g1, g2, g3,
                                              out, total);
}

// Round 11
// 64.115 us; speedup vs baseline: 1.1863x; 1.1633x over previous
//
#include <hip/hip_runtime.h>

#define P 7
#define NCH 256
#define NPP 49
#define PER_BOX (NCH * NPP)   // 12544

typedef float f2 __attribute__((ext_vector_type(2), aligned(4)));

__global__ __launch_bounds__(256) void pooler_kernel(
    const float* __restrict__ boxes,
    const int* __restrict__ batch_ids,
    const float* __restrict__ g0, const float* __restrict__ g1,
    const float* __restrict__ g2, const float* __restrict__ g3,
    float* __restrict__ out, int total)
{
    const int tid = blockIdx.x * 256 + threadIdx.x;
    if (tid >= total) return;            // grid tiles exactly; never taken

    // tid -> (n, c, bin)
    const int n   = tid / PER_BOX;
    const int rem = tid - n * PER_BOX;
    const int c   = rem / NPP;
    const int bin = rem - c * NPP;
    const int py  = bin / P;
    const int px  = bin - py * P;

    // ---- box + level ----
    const float x1i = boxes[n*4+0], y1i = boxes[n*4+1];
    const float x2i = boxes[n*4+2], y2i = boxes[n*4+3];
    const float area = (x2i - x1i) * (y2i - y1i);
    float lvlf = floorf(4.0f + log2f(sqrtf(area) / 224.0f + 1e-6f));
    lvlf = fminf(fmaxf(lvlf, 2.0f), 5.0f);
    const int lvl = (int)lvlf - 2;       // 0..3

    const float* feat = (lvl==0) ? g0 : (lvl==1) ? g1 : (lvl==2) ? g2 : g3;
    const int    L    = (lvl==0) ? 200 : (lvl==1) ? 100 : (lvl==2) ? 50 : 25;
    const float scale = (lvl==0) ? 0.25f : (lvl==1) ? 0.125f
                      : (lvl==2) ? 0.0625f : 0.03125f;
    const int b = batch_ids[n];

    const float x1 = x1i * scale, y1 = y1i * scale;
    const float bw = fmaxf(x2i*scale - x1, 1.0f) * (1.0f/7.0f);
    const float bh = fmaxf(y2i*scale - y1, 1.0f) * (1.0f/7.0f);
    const float Lf = (float)L, Lm1 = Lf - 1.0f;
    const int   Lm2 = L - 2;

    // ---- per-axis sample prep (computed once, used by all 4 taps) ----
    int   y0[2], x0[2];
    float fy[2], hy[2], vy[2], fx[2], hx[2], vx[2];
#pragma unroll
    for (int s = 0; s < 2; ++s) {
        const float yc = y1 + ((float)py + (s ? 0.75f : 0.25f)) * bh;
        vy[s] = (yc > -1.0f && yc < Lf) ? 1.0f : 0.0f;
        const float ycc = fminf(fmaxf(yc, 0.0f), Lm1);
        y0[s] = min((int)ycc, Lm2);
        fy[s] = ycc - (float)y0[s];
        hy[s] = 1.0f - fy[s];

        const float xc = x1 + ((float)px + (s ? 0.75f : 0.25f)) * bw;
        vx[s] = (xc > -1.0f && xc < Lf) ? 1.0f : 0.0f;
        const float xcc = fminf(fmaxf(xc, 0.0f), Lm1);
        x0[s] = min((int)xcc, Lm2);
        fx[s] = xcc - (float)x0[s];
        hx[s] = 1.0f - fx[s];
    }

    const float* plane = feat + ((size_t)b * NCH + c) * (size_t)(L * L);

    // ---- 4 taps, each = two 8B pair-loads (v00,v01) and (v10,v11) ----
    // all 8 loads are independent -> deep MLP within one thread
    const f2 a00 = *(const f2*)(plane + y0[0]*L + x0[0]);
    const f2 b00 = *(const f2*)(plane + y0[0]*L + x0[0] + L);
    const f2 a01 = *(const f2*)(plane + y0[0]*L + x0[1]);
    const f2 b01 = *(const f2*)(plane + y0[0]*L + x0[1] + L);
    const f2 a10 = *(const f2*)(plane + y0[1]*L + x0[0]);
    const f2 b10 = *(const f2*)(plane + y0[1]*L + x0[0] + L);
    const f2 a11 = *(const f2*)(plane + y0[1]*L + x0[1]);
    const f2 b11 = *(const f2*)(plane + y0[1]*L + x0[1] + L);

    float acc = 0.0f;
    {   // tap (sy=0, sx=0)
        const float w = vy[0]*vx[0];
        acc += w * (hy[0]*(hx[0]*a00.x + fx[0]*a00.y)
                  + fy[0]*(hx[0]*b00.x + fx[0]*b00.y));
    }
    {   // tap (sy=0, sx=1)
        const float w = vy[0]*vx[1];
        acc += w * (hy[0]*(hx[1]*a01.x + fx[1]*a01.y)
                  + fy[0]*(hx[1]*b01.x + fx[1]*b01.y));
    }
    {   // tap (sy=1, sx=0)
        const float w = vy[1]*vx[0];
        acc += w * (hy[1]*(hx[0]*a10.x + fx[0]*a10.y)
                  + fy[1]*(hx[0]*b10.x + fx[0]*b10.y));
    }
    {   // tap (sy=1, sx=1)
        const float w = vy[1]*vx[1];
        acc += w * (hy[1]*(hx[1]*a11.x + fx[1]*a11.y)
                  + fy[1]*(hx[1]*b11.x + fx[1]*b11.y));
    }

    out[tid] = acc * 0.25f;
}

extern "C" void kernel_launch(void* const* d_in, const int* in_sizes, int n_in,
                              void* d_out, int out_size, void* d_ws, size_t ws_size,
                              hipStream_t stream) {
    const float* boxes     = (const float*)d_in[0];
    const int*   batch_ids = (const int*)d_in[1];
    const float* g0        = (const float*)d_in[2];
    const float* g1        = (const float*)d_in[3];
    const float* g2        = (const float*)d_in[4];
    const float* g3        = (const float*)d_in[5];
    float* out = (float*)d_out;

    const int total = out_size;                    // 6,422,528
    const int blocks = (total + 255) / 256;        // 25088
    pooler_kernel<<<blocks, 256, 0, stream>>>(boxes, batch_ids, g0, g1, g2, g3,
                                              out, total);
}

// Round 12
// 63.786 us; speedup vs baseline: 1.1924x; 1.0052x over previous
//
#include <hip/hip_runtime.h>

#define P 7
#define NCH 256
#define NPP 49
#define PER_BOX (NCH * NPP)   // 12544

typedef float f2 __attribute__((ext_vector_type(2), aligned(4)));

__global__ __launch_bounds__(256) void pooler_kernel(
    const float* __restrict__ boxes,
    const int* __restrict__ batch_ids,
    const float* __restrict__ g0, const float* __restrict__ g1,
    const float* __restrict__ g2, const float* __restrict__ g3,
    float* __restrict__ out, int total)
{
    // ---- XCD box-affinity swizzle -------------------------------------
    // Physical blocks round-robin across 8 XCDs (i%8). Remap so all 49
    // blocks of one box land on ONE XCD: bijection over 25088 = 8*64*49.
    const int i    = blockIdx.x;
    const int xcd  = i & 7;
    const int slot = i >> 3;            // 0..3135
    const int nb   = slot / 49;         // 0..63   (box slot on this XCD)
    const int wb   = slot - nb * 49;    // 0..48   (block within box)
    const int j    = (xcd + (nb << 3)) * 49 + wb;   // logical block

    const int tid = j * 256 + threadIdx.x;
    if (tid >= total) return;           // exact tiling; never taken

    // tid -> (n, c, bin)
    const int n   = tid / PER_BOX;
    const int rem = tid - n * PER_BOX;
    const int c   = rem / NPP;
    const int bin = rem - c * NPP;
    const int py  = bin / P;
    const int px  = bin - py * P;

    // ---- box + level ----
    const float x1i = boxes[n*4+0], y1i = boxes[n*4+1];
    const float x2i = boxes[n*4+2], y2i = boxes[n*4+3];
    const float area = (x2i - x1i) * (y2i - y1i);
    float lvlf = floorf(4.0f + log2f(sqrtf(area) / 224.0f + 1e-6f));
    lvlf = fminf(fmaxf(lvlf, 2.0f), 5.0f);
    const int lvl = (int)lvlf - 2;      // 0..3

    const float* feat = (lvl==0) ? g0 : (lvl==1) ? g1 : (lvl==2) ? g2 : g3;
    const int    L    = (lvl==0) ? 200 : (lvl==1) ? 100 : (lvl==2) ? 50 : 25;
    const float scale = (lvl==0) ? 0.25f : (lvl==1) ? 0.125f
                      : (lvl==2) ? 0.0625f : 0.03125f;
    const int b = batch_ids[n];

    const float x1 = x1i * scale, y1 = y1i * scale;
    const float bw = fmaxf(x2i*scale - x1, 1.0f) * (1.0f/7.0f);
    const float bh = fmaxf(y2i*scale - y1, 1.0f) * (1.0f/7.0f);
    const float Lf = (float)L, Lm1 = Lf - 1.0f;
    const int   Lm2 = L - 2;

    // ---- per-axis sample prep (computed once, used by all 4 taps) ----
    int   y0[2], x0[2];
    float fy[2], hy[2], vy[2], fx[2], hx[2], vx[2];
#pragma unroll
    for (int s = 0; s < 2; ++s) {
        const float yc = y1 + ((float)py + (s ? 0.75f : 0.25f)) * bh;
        vy[s] = (yc > -1.0f && yc < Lf) ? 1.0f : 0.0f;
        const float ycc = fminf(fmaxf(yc, 0.0f), Lm1);
        y0[s] = min((int)ycc, Lm2);
        fy[s] = ycc - (float)y0[s];
        hy[s] = 1.0f - fy[s];

        const float xc = x1 + ((float)px + (s ? 0.75f : 0.25f)) * bw;
        vx[s] = (xc > -1.0f && xc < Lf) ? 1.0f : 0.0f;
        const float xcc = fminf(fmaxf(xc, 0.0f), Lm1);
        x0[s] = min((int)xcc, Lm2);
        fx[s] = xcc - (float)x0[s];
        hx[s] = 1.0f - fx[s];
    }

    const float* plane = feat + ((size_t)b * NCH + c) * (size_t)(L * L);

    // ---- 4 taps, each = two 8B pair-loads; all 8 loads independent ----
    const f2 a00 = *(const f2*)(plane + y0[0]*L + x0[0]);
    const f2 b00 = *(const f2*)(plane + y0[0]*L + x0[0] + L);
    const f2 a01 = *(const f2*)(plane + y0[0]*L + x0[1]);
    const f2 b01 = *(const f2*)(plane + y0[0]*L + x0[1] + L);
    const f2 a10 = *(const f2*)(plane + y0[1]*L + x0[0]);
    const f2 b10 = *(const f2*)(plane + y0[1]*L + x0[0] + L);
    const f2 a11 = *(const f2*)(plane + y0[1]*L + x0[1]);
    const f2 b11 = *(const f2*)(plane + y0[1]*L + x0[1] + L);

    float acc = 0.0f;
    {   const float w = vy[0]*vx[0];
        acc += w * (hy[0]*(hx[0]*a00.x + fx[0]*a00.y)
                  + fy[0]*(hx[0]*b00.x + fx[0]*b00.y)); }
    {   const float w = vy[0]*vx[1];
        acc += w * (hy[0]*(hx[1]*a01.x + fx[1]*a01.y)
                  + fy[0]*(hx[1]*b01.x + fx[1]*b01.y)); }
    {   const float w = vy[1]*vx[0];
        acc += w * (hy[1]*(hx[0]*a10.x + fx[0]*a10.y)
                  + fy[1]*(hx[0]*b10.x + fx[0]*b10.y)); }
    {   const float w = vy[1]*vx[1];
        acc += w * (hy[1]*(hx[1]*a11.x + fx[1]*a11.y)
                  + fy[1]*(hx[1]*b11.x + fx[1]*b11.y)); }

    out[tid] = acc * 0.25f;
}

extern "C" void kernel_launch(void* const* d_in, const int* in_sizes, int n_in,
                              void* d_out, int out_size, void* d_ws, size_t ws_size,
                              hipStream_t stream) {
    const float* boxes     = (const float*)d_in[0];
    const int*   batch_ids = (const int*)d_in[1];
    const float* g0        = (const float*)d_in[2];
    const float* g1        = (const float*)d_in[3];
    const float* g2        = (const float*)d_in[4];
    const float* g3        = (const float*)d_in[5];
    float* out = (float*)d_out;

    const int total = out_size;                    // 6,422,528
    const int blocks = (total + 255) / 256;        // 25088 = 8 * 64 * 49
    pooler_kernel<<<blocks, 256, 0, stream>>>(boxes, batch_ids, g0, g1, g2, g3,
                                              out, total);
}